// Round 1
// 3516.401 us; speedup vs baseline: 1.4944x; 1.4944x over previous
//
#include <hip/hip_runtime.h>

// Dims
constexpr int TSTEPS = 512;
constexpr int FDIM   = 128;
constexpr int HDIM   = 256;
constexpr int G4H    = 1024;   // 4*H
constexpr int NGRP   = 64;     // 64 groups x 4 blocks; 4 batch rows per group
constexpr int TC     = 8;      // time-chunk (xz precompute granularity)
constexpr int NCH    = TSTEPS / TC;

typedef float        f32x2 __attribute__((ext_vector_type(2)));
typedef _Float16     h2    __attribute__((ext_vector_type(2)));
typedef unsigned int u32;
typedef u32          u32x2 __attribute__((ext_vector_type(2)));
typedef u32          u32x4 __attribute__((ext_vector_type(4)));

#if defined(__has_builtin)
#if __has_builtin(__builtin_amdgcn_fdot2)
#define FDOT2(a, b, c) __builtin_amdgcn_fdot2((a), (b), (c), false)
#endif
#endif
#ifndef FDOT2
#define FDOT2(a, b, c) ((c) + (float)(a)[0] * (float)(b)[0] + (float)(a)[1] * (float)(b)[1])
#endif

__device__ __forceinline__ h2 as_h2(u32 v) { union { u32 u; h2 p; } c; c.u = v; return c.p; }
__device__ __forceinline__ u32 pack_h2(float a, float b) {
    union { h2 p; u32 u; } c; c.p = h2{(_Float16)a, (_Float16)b}; return c.u;
}
__device__ __forceinline__ float sigmf(float z) { return 1.f / (1.f + __expf(-z)); }
__device__ __forceinline__ float tanhf_fast(float z) {
    float a = fabsf(z);
    float e = __expf(-2.f * a);
    float r = (1.f - e) / (1.f + e);
    return z < 0.f ? -r : r;
}

// ws layout (u32 units):
//   [0]        : wcount (one-time all-blocks-loaded barrier)
//   [16..272)  : flags[g*4+q], step sequence numbers (zeroed each launch)
//   [512..)    : WG = per-member rker fp16 k-pair slices, 4 x 32768 u32 (512 KB)
//                HX (h exchange, 2 x 64 x 512 u32 = 256 KB) OVERLAYS WG[0..65536)
//                — safe: every block finishes reading WG before the wcount
//                barrier releases, and only after that is HX written.
// Total ws use: 526,336 B (< 768 KB proven available).
//
// Member q of group g owns hidden units [64q,64q+64) -> the 256 gate-columns
// gcol = (c>>6)*256 + 64q + (c&63), c in [0,256). Its rker slice (256 K x
// 256 cols fp16 = 128 KB) lives in LDS for the whole kernel: the per-step
// 512 KB/CU L2 weight stream of the previous kernel is gone.

extern "C" __global__ void __launch_bounds__(256)
conv_wpk(const float* __restrict__ rker, u32* __restrict__ ws)
{
    for (int i = blockIdx.x * 256 + threadIdx.x; i < 512 + 4 * 32768; i += gridDim.x * 256) {
        if (i < 512) { ws[i] = 0; continue; }   // zero wcount + flags (every launch)
        const int ii  = i - 512;
        const int q   = ii >> 15, j = ii & 32767;
        const int kp2 = j >> 9,  rem = j & 511;
        const int c   = rem >> 1, par = rem & 1;
        const int kp  = 2 * kp2 + par;          // h-pair index: units (2kp, 2kp+1)
        const int gcol = (c >> 6) * 256 + 64 * q + (c & 63);
        const float a = rker[(size_t)(2 * kp) * G4H + gcol];
        const float b = rker[(size_t)(2 * kp + 1) * G4H + gcol];
        ws[i] = pack_h2(a, b);
    }
}

extern "C" __global__ void __launch_bounds__(512)
lstm_pers(const float* __restrict__ x, const float* __restrict__ kern,
          u32* __restrict__ ws,
          const float* __restrict__ w1, const float* __restrict__ b1,
          const float* __restrict__ w2, const float* __restrict__ b2,
          float* __restrict__ out)
{
    const int bid = blockIdx.x;
    const int g   = bid & 63;        // group: rows [4g, 4g+4)
    const int q   = bid >> 6;        // member: units [64q, 64q+64)
    const int tid = threadIdx.x;

    u32*       const FLG = ws + 16;
    const u32* const WG  = ws + 512;
    u32*       const HX  = ws + 512;  // overlays WG (guarded by wcount barrier)

    // LDS: 131072 + 16384 + 2048 + 8192 = 157,696 B (<= 160 KB, 1 block/CU)
    __shared__ __align__(16) u32 wl[32768];          // rker slice: [kp2][c][par]
    __shared__ __align__(16) u32 xzp[2 * TC * 256];  // xz fp16 row-pairs: [rp][t][c]
    __shared__ __align__(16) u32 hpk[512];           // h fp16 unit-pairs: [kp][row]
    __shared__ __align__(16) u32 uni[2048];          // union: xs (phase A) / zbuf (phase B) / hid (head)
    float* const zbuf = (float*)uni;                 // [half][r][c] f32
    u32*   const xs   = uni;                         // [fp][r][t] fp16 x-pairs
    float* const hid  = (float*)uni;

    // ---- One-time: weights -> LDS, then device-wide "all loaded" barrier
    {
        const u32* wsrc = WG + q * 32768;
        for (int i = 4 * tid; i < 32768; i += 4 * 512)
            *reinterpret_cast<u32x4*>(&wl[i]) = *reinterpret_cast<const u32x4*>(&wsrc[i]);
    }
    hpk[tid] = 0;  // h(0) = 0
    __syncthreads();  // all this block's WG reads drained before signalling
    if (tid == 0) {
        atomicAdd(&ws[0], 1u);
        while (__hip_atomic_load(&ws[0], __ATOMIC_ACQUIRE, __HIP_MEMORY_SCOPE_AGENT) < 256u) {}
    }
    __syncthreads();

    const int c    = tid & 255;       // dot-phase column (local)
    const int half = tid >> 8;        // K-half: kp2 in [32*half, 32*half+32)
    const int gu   = tid & 63;        // gating unit (local), tid<256
    const int gr   = tid >> 6;        // gating row, tid<256
    const int gcol = (c >> 6) * 256 + 64 * q + (c & 63);
    const int pp   = (tid < 3) ? (tid + (tid >= q)) : 0;  // partner ids
    float cst = 0.f;                  // cell state, owned by gating threads

#pragma unroll 1
    for (int ch = 0; ch < NCH; ++ch) {
        __syncthreads();  // SA0: prev chunk fully done; uni free for xs

        // ---- Stage x chunk as fp16 f-pairs: xs[fp*32 + r*8 + t]
#pragma unroll
        for (int i = 0; i < 4; ++i) {
            const int slot = tid + i * 512;
            const int rt = slot >> 6, fp = slot & 63;
            const int r = rt >> 3, t = rt & 7;
            const f32x2 xv = *reinterpret_cast<const f32x2*>(
                &x[(((size_t)(4 * g + r)) * TSTEPS + (ch * TC + t)) * FDIM + 2 * fp]);
            xs[fp * 32 + r * 8 + t] = pack_h2(xv[0], xv[1]);
        }
        __syncthreads();  // SA1: xs ready

        // ---- Phase A: xz for this chunk. Thread (c, half) does t = half*4+tp.
        // kern read as f32 from L2 (512 KB, shared by 64 same-q blocks), packed
        // to fp16 pairs on the fly -> identical numerics to the old premade path.
        {
            float acc[4][4];  // [tp][r]
#pragma unroll
            for (int tp = 0; tp < 4; ++tp)
#pragma unroll
                for (int r = 0; r < 4; ++r) acc[tp][r] = 0.f;
#pragma unroll 4
            for (int fp = 0; fp < 64; ++fp) {
                const float k0 = kern[(size_t)(2 * fp) * G4H + gcol];
                const float k1 = kern[(size_t)(2 * fp + 1) * G4H + gcol];
                const h2 wp = h2{(_Float16)k0, (_Float16)k1};
#pragma unroll
                for (int r = 0; r < 4; ++r) {
                    const u32x4 X = *reinterpret_cast<const u32x4*>(&xs[fp * 32 + r * 8 + half * 4]);
#pragma unroll
                    for (int tp = 0; tp < 4; ++tp)
                        acc[tp][r] = FDOT2(wp, as_h2(X[tp]), acc[tp][r]);
                }
            }
#pragma unroll
            for (int tp = 0; tp < 4; ++tp)
#pragma unroll
                for (int rp = 0; rp < 2; ++rp)
                    xzp[rp * 2048 + (half * 4 + tp) * 256 + c] =
                        pack_h2(acc[tp][2 * rp], acc[tp][2 * rp + 1]);
        }

        // ---- Phase B: 8 recurrence steps, weights from LDS only
#pragma unroll 1
        for (int tc = 0; tc < TC; ++tc) {
            const int t = ch * TC + tc;
            __syncthreads();  // B1: hpk(t) complete (imports+own), xzp ready, zbuf free

            float a0 = 0.f, a1 = 0.f, a2 = 0.f, a3 = 0.f;
#pragma unroll 8
            for (int kq = 0; kq < 32; ++kq) {
                const int kp2 = half * 32 + kq;
                const u32x2 W  = *reinterpret_cast<const u32x2*>(&wl[kp2 * 512 + 2 * c]);
                const u32x4 H0 = *reinterpret_cast<const u32x4*>(&hpk[(2 * kp2) * 4]);     // broadcast
                const u32x4 H1 = *reinterpret_cast<const u32x4*>(&hpk[(2 * kp2 + 1) * 4]); // broadcast
                const h2 w0 = as_h2(W[0]), w1h = as_h2(W[1]);
                a0 = FDOT2(w0, as_h2(H0[0]), a0); a0 = FDOT2(w1h, as_h2(H1[0]), a0);
                a1 = FDOT2(w0, as_h2(H0[1]), a1); a1 = FDOT2(w1h, as_h2(H1[1]), a1);
                a2 = FDOT2(w0, as_h2(H0[2]), a2); a2 = FDOT2(w1h, as_h2(H1[2]), a2);
                a3 = FDOT2(w0, as_h2(H0[3]), a3); a3 = FDOT2(w1h, as_h2(H1[3]), a3);
            }
            zbuf[half * 1024 + 0 * 256 + c] = a0;   // lanes stride 1 dword: conflict-free
            zbuf[half * 1024 + 1 * 256 + c] = a1;
            zbuf[half * 1024 + 2 * 256 + c] = a2;
            zbuf[half * 1024 + 3 * 256 + c] = a3;
            __syncthreads();  // B2: partial z ready

            if (tid < 256) {  // gating: thread (gu, gr) owns unit 64q+gu, row 4g+gr
                float z[4];
#pragma unroll
                for (int g4 = 0; g4 < 4; ++g4) {
                    const int cc = g4 * 64 + gu;
                    const h2 xp = as_h2(xzp[(gr >> 1) * 2048 + tc * 256 + cc]);
                    z[g4] = zbuf[gr * 256 + cc] + zbuf[1024 + gr * 256 + cc] +
                            (float)((gr & 1) ? xp[1] : xp[0]);
                }
                cst = sigmf(z[1]) * cst + sigmf(z[0]) * tanhf_fast(z[2]);
                const float hn = sigmf(z[3]) * tanhf_fast(cst);
                const float ho = __shfl_xor(hn, 1);
                if (!(gu & 1)) {  // even lane packs the unit pair (self, neighbor)
                    const int kp = 32 * q + (gu >> 1);
                    const u32 hv = pack_h2(hn, ho);
                    hpk[kp * 4 + gr] = hv;  // own slice, local
                    __hip_atomic_store(&HX[(size_t)((t & 1) * 64 + g) * 512 + kp * 4 + gr],
                                       hv, __ATOMIC_RELAXED, __HIP_MEMORY_SCOPE_AGENT);
                }
            }
            __syncthreads();  // B3: export stores drained (vmcnt(0) before s_barrier)
            if (tid == 0)
                __hip_atomic_store(&FLG[g * 4 + q], (u32)(t + 1),
                                   __ATOMIC_RELEASE, __HIP_MEMORY_SCOPE_AGENT);
            if (tid < 3) {
                while (__hip_atomic_load(&FLG[g * 4 + pp], __ATOMIC_ACQUIRE,
                                         __HIP_MEMORY_SCOPE_AGENT) < (u32)(t + 1)) {}
            }
            __syncthreads();  // B4: all partner slices published
            if (tid < 384) {  // import 3 partner slices -> hpk
                const int pi = tid >> 7, j = tid & 127;
                const int p  = pi + (pi >= q);
                const int kp = 32 * p + (j >> 2), r = j & 3;
                hpk[kp * 4 + r] = __hip_atomic_load(
                    &HX[(size_t)((t & 1) * 64 + g) * 512 + kp * 4 + r],
                    __ATOMIC_RELAXED, __HIP_MEMORY_SCOPE_AGENT);
            }
            // next B1 orders hpk imports vs dot reads
        }
    }
    __syncthreads();

    // ---- Fused head: member q emits out[4g+q] = relu(h@w1+b1)@w2 + b2
    if (tid < 100) {
        float aa = b1[tid];
        const _Float16* hph = (const _Float16*)hpk;
#pragma unroll 8
        for (int k = 0; k < HDIM; ++k)
            aa += (float)hph[((k >> 1) * 4 + q) * 2 + (k & 1)] * w1[k * 100 + tid];
        hid[tid] = fmaxf(aa, 0.f);
    }
    __syncthreads();
    if (tid == 0) {
        float v = b2[0];
#pragma unroll 4
        for (int j = 0; j < 100; ++j) v += hid[j] * w2[j];
        out[4 * g + q] = v;
    }
}

extern "C" void kernel_launch(void* const* d_in, const int* in_sizes, int n_in,
                              void* d_out, int out_size, void* d_ws, size_t ws_size,
                              hipStream_t stream)
{
    const float* x    = (const float*)d_in[0];
    const float* kern = (const float*)d_in[1];
    const float* rker = (const float*)d_in[2];
    const float* w1   = (const float*)d_in[3];
    const float* b1   = (const float*)d_in[4];
    const float* w2   = (const float*)d_in[5];
    const float* b2   = (const float*)d_in[6];
    u32* ws = (u32*)d_ws;  // 526,336 B used (< 768 KB proven)

    conv_wpk<<<dim3(514), dim3(256), 0, stream>>>(rker, ws);
    lstm_pers<<<dim3(256), dim3(512), 0, stream>>>(x, kern, ws, w1, b1, w2, b2, (float*)d_out);
}